// Round 4
// baseline (173.580 us; speedup 1.0000x reference)
//
#include <hip/hip_runtime.h>
#include <math.h>

#define QD 24
#define KD 24
#define HD 64
#define NN 512
#define DO 128

typedef float v2f __attribute__((ext_vector_type(2)));

__device__ __forceinline__ float fast_tanh(float x) {
    float ax = __builtin_fabsf(x);
    float t  = __builtin_amdgcn_exp2f(-2.885390081777927f * ax); // -2*log2(e)*|x|
    float r  = (1.0f - t) * __builtin_amdgcn_rcpf(1.0f + t);
    return __builtin_copysignf(r, x);
}

__device__ __forceinline__ v2f fma2(v2f a, v2f b, v2f c) {
    return __builtin_elementwise_fma(a, b, c);
}
__device__ __forceinline__ v2f bc2(float s) { return (v2f){s, s}; }

__device__ __forceinline__ v2f fast_tanh2(v2f x) {
    v2f ax; ax.x = __builtin_fabsf(x.x); ax.y = __builtin_fabsf(x.y);
    v2f m = ax * -2.885390081777927f;
    v2f t; t.x = __builtin_amdgcn_exp2f(m.x); t.y = __builtin_amdgcn_exp2f(m.y);
    v2f num = 1.0f - t;
    v2f den = 1.0f + t;
    v2f rc; rc.x = __builtin_amdgcn_rcpf(den.x); rc.y = __builtin_amdgcn_rcpf(den.y);
    v2f r = num * rc;
    r.x = __builtin_copysignf(r.x, x.x);
    r.y = __builtin_copysignf(r.y, x.y);
    return r;
}

// K0: qks[b][j] = (wk2 @ q)[j] * (1/8)*log2(e);  Mb[b] = sum_j |qks[b][j]|
// q = tanh(fwp@wq1+bq1)@wq2+bq2.  bk2 cancels in softmax (per-row constant).
__global__ __launch_bounds__(64) void qk_proj(
    const float* __restrict__ fwp,
    const float* __restrict__ wq1, const float* __restrict__ bq1,
    const float* __restrict__ wq2, const float* __restrict__ bq2,
    const float* __restrict__ wk2,
    float* __restrict__ qks_g, float* __restrict__ Mb_g)
{
    const int b = blockIdx.x;
    const int j = threadIdx.x;
    __shared__ float xf[QD];
    __shared__ float h1[HD];
    __shared__ float qv[HD];
    if (j < QD) xf[j] = fwp[(size_t)b * QD + j];
    __syncthreads();
    float acc = bq1[j];
#pragma unroll
    for (int k = 0; k < QD; ++k) acc = fmaf(xf[k], wq1[k * HD + j], acc);
    h1[j] = fast_tanh(acc);
    __syncthreads();
    acc = bq2[j];
#pragma unroll
    for (int i = 0; i < HD; ++i) acc = fmaf(h1[i], wq2[i * HD + j], acc);
    qv[j] = acc;
    __syncthreads();
    float s = 0.0f;
#pragma unroll
    for (int h = 0; h < HD; ++h) s = fmaf(wk2[j * HD + h], qv[h], s);
    const float val = s * 0.18033688011112042f;   // (1/8)*log2(e)
    qks_g[(size_t)b * HD + j] = val;
    float mb = __builtin_fabsf(val);
#pragma unroll
    for (int o = 32; o > 0; o >>= 1) mb += __shfl_xor(mb, o, 64);
    if (j == 0) Mb_g[b] = mb;
}

// K1: normalized attention weights for all (b, n).  One block per b,
// 256 threads, rows t and t+256 packed into float2 lanes (v_pk_fma_f32).
__global__ __launch_bounds__(256, 4) void score_attn(
    const float* __restrict__ pwp,   // [B, N, 24]
    const float* __restrict__ wk1,   // [24, 64]
    const float* __restrict__ bk1,   // [64]
    const float* __restrict__ qks_g, // [B, 64]
    const float* __restrict__ Mb_g,  // [B]
    float* __restrict__ out_attn)    // [B, N]
{
    const int b = blockIdx.x;
    const int t = threadIdx.x;

    __shared__ float qks[HD];
    __shared__ float s_red[4];

    // issue pwp loads for both rows immediately
    const float* prowA = pwp + ((size_t)b * NN + t) * KD;
    const float* prowB = prowA + (size_t)256 * KD;
    float xA[KD], xB[KD];
#pragma unroll
    for (int i = 0; i < KD / 4; ++i) {
        reinterpret_cast<float4*>(xA)[i] = reinterpret_cast<const float4*>(prowA)[i];
        reinterpret_cast<float4*>(xB)[i] = reinterpret_cast<const float4*>(prowB)[i];
    }

    if (t < HD) qks[t] = qks_g[(size_t)b * HD + t];
    const float Mb = Mb_g[b];
    __syncthreads();

    v2f x2[KD];
#pragma unroll
    for (int k = 0; k < KD; ++k) x2[k] = (v2f){xA[k], xB[k]};

    const float4* wk1_4 = reinterpret_cast<const float4*>(wk1);
    const float4* bk1_4 = reinterpret_cast<const float4*>(bk1);
    const float4* qks_4 = reinterpret_cast<const float4*>(qks);

    v2f sc = (v2f){0.0f, 0.0f};
#pragma unroll 2
    for (int j4 = 0; j4 < HD / 4; ++j4) {
        float4 bb = bk1_4[j4];                    // uniform -> scalar load
        v2f a0 = bc2(bb.x), a1 = bc2(bb.y), a2 = bc2(bb.z), a3 = bc2(bb.w);
#pragma unroll
        for (int k = 0; k < KD; ++k) {
            float4 w = wk1_4[k * (HD / 4) + j4];  // uniform -> scalar load
            a0 = fma2(x2[k], bc2(w.x), a0);
            a1 = fma2(x2[k], bc2(w.y), a1);
            a2 = fma2(x2[k], bc2(w.z), a2);
            a3 = fma2(x2[k], bc2(w.w), a3);
        }
        float4 qq = qks_4[j4];                    // LDS broadcast
        sc = fma2(fast_tanh2(a0), bc2(qq.x), sc);
        sc = fma2(fast_tanh2(a1), bc2(qq.y), sc);
        sc = fma2(fast_tanh2(a2), bc2(qq.z), sc);
        sc = fma2(fast_tanh2(a3), bc2(qq.w), sc);
    }

    const float pA = __builtin_amdgcn_exp2f(sc.x - Mb);
    const float pB = __builtin_amdgcn_exp2f(sc.y - Mb);

    float l = pA + pB;
#pragma unroll
    for (int o = 32; o > 0; o >>= 1) l += __shfl_xor(l, o, 64);
    if ((t & 63) == 0) s_red[t >> 6] = l;
    __syncthreads();
    const float L = (s_red[0] + s_red[1]) + (s_red[2] + s_red[3]);
    const float invL = __builtin_amdgcn_rcpf(L);

    out_attn[(size_t)b * NN + t]       = pA * invL;
    out_attn[(size_t)b * NN + t + 256] = pB * invL;
}

// K2: pure stream.  context[b,:] = sum_n attn[b,n] * TO[b,n,:].
// 2048 blocks x 256 threads = exactly one full-device generation.
__global__ __launch_bounds__(256) void ctx_stream(
    const float* __restrict__ to,    // [B, N, 128]
    const float* __restrict__ attn,  // [B, N] (normalized)
    float* __restrict__ out_ctx)     // [B, 128]
{
    const int b = blockIdx.x;
    const int t = threadIdx.x;

    __shared__ float  pa[NN];
    __shared__ float4 part[8][32];

    pa[t]       = attn[(size_t)b * NN + t];
    pa[t + 256] = attn[(size_t)b * NN + t + 256];
    __syncthreads();

    const int g  = t & 31;           // float4 column 0..31
    const int np = t >> 5;           // row partition 0..7 (64 rows each)
    const float4* trow = reinterpret_cast<const float4*>(to + (size_t)b * NN * DO) + g;
    float4 acc = make_float4(0.f, 0.f, 0.f, 0.f);
#pragma unroll 8
    for (int i = 0; i < 64; ++i) {
        const int n = np * 64 + i;
        const float p = pa[n];       // half-wave broadcast
        float4 v = trow[(size_t)n * (DO / 4)];
        acc.x = fmaf(p, v.x, acc.x);
        acc.y = fmaf(p, v.y, acc.y);
        acc.z = fmaf(p, v.z, acc.z);
        acc.w = fmaf(p, v.w, acc.w);
    }
    part[np][g] = acc;
    __syncthreads();

    if (t < 32) {
        float4 r = part[0][t];
#pragma unroll
        for (int q = 1; q < 8; ++q) {
            float4 v = part[q][t];
            r.x += v.x; r.y += v.y; r.z += v.z; r.w += v.w;
        }
        reinterpret_cast<float4*>(out_ctx + (size_t)b * DO)[t] = r;
    }
}

extern "C" void kernel_launch(void* const* d_in, const int* in_sizes, int n_in,
                              void* d_out, int out_size, void* d_ws, size_t ws_size,
                              hipStream_t stream) {
    const float* fwp = (const float*)d_in[0];
    const float* pwp = (const float*)d_in[1];
    const float* to  = (const float*)d_in[2];
    const float* wq1 = (const float*)d_in[3];
    const float* bq1 = (const float*)d_in[4];
    const float* wq2 = (const float*)d_in[5];
    const float* bq2 = (const float*)d_in[6];
    const float* wk1 = (const float*)d_in[7];
    const float* bk1 = (const float*)d_in[8];
    const float* wk2 = (const float*)d_in[9];
    // d_in[10] = bk2: per-row constant in scores -> cancels in softmax.

    float* out      = (float*)d_out;
    const int B     = in_sizes[0] / QD;         // 2048
    float* out_ctx  = out;
    float* out_attn = out + (size_t)B * DO;

    float* qks_g = (float*)d_ws;                // B*64 floats
    float* Mb_g  = qks_g + (size_t)B * HD;      // B floats

    qk_proj<<<B, 64, 0, stream>>>(fwp, wq1, bq1, wq2, bq2, wk2, qks_g, Mb_g);
    score_attn<<<B, 256, 0, stream>>>(pwp, wk1, bk1, qks_g, Mb_g, out_attn);
    ctx_stream<<<B, 256, 0, stream>>>(to, out_attn, out_ctx);
}

// Round 5
// 146.137 us; speedup vs baseline: 1.1878x; 1.1878x over previous
//
#include <hip/hip_runtime.h>
#include <math.h>

#define QD 24
#define KD 24
#define HD 64
#define NN 512
#define DO 128
#define CHUNK 128
#define NCHUNK (NN / CHUNK)

__device__ __forceinline__ float fast_tanh(float x) {
    // tanh(x) = sign(x) * (1 - e^{-2|x|}) / (1 + e^{-2|x|}); exp via exp2
    float ax = __builtin_fabsf(x);
    float t  = __builtin_amdgcn_exp2f(-2.885390081777927f * ax); // -2*log2(e)*|x|
    float r  = (1.0f - t) * __builtin_amdgcn_rcpf(1.0f + t);
    return __builtin_copysignf(r, x);
}

// K0: qks[b][j] = (wk2 @ q)[j] * (1/8)*log2(e);  Mb[b] = sum_j |qks[b][j]|.
// q = tanh(fwp@wq1+bq1)@wq2+bq2.  bk2 adds a per-row constant to every
// score -> cancels in softmax. Fixed shift Mb bounds every score from above
// (|tanh|<=1), so softmax needs no max reduction (exact by shift-invariance).
__global__ __launch_bounds__(64) void qk_proj(
    const float* __restrict__ fwp,
    const float* __restrict__ wq1, const float* __restrict__ bq1,
    const float* __restrict__ wq2, const float* __restrict__ bq2,
    const float* __restrict__ wk2,
    float* __restrict__ qks_g, float* __restrict__ Mb_g)
{
    const int b = blockIdx.x;
    const int j = threadIdx.x;
    __shared__ float xf[QD];
    __shared__ float h1[HD];
    __shared__ float qv[HD];
    if (j < QD) xf[j] = fwp[(size_t)b * QD + j];
    __syncthreads();
    float acc = bq1[j];
#pragma unroll
    for (int k = 0; k < QD; ++k) acc = fmaf(xf[k], wq1[k * HD + j], acc);
    h1[j] = fast_tanh(acc);
    __syncthreads();
    acc = bq2[j];
#pragma unroll
    for (int i = 0; i < HD; ++i) acc = fmaf(h1[i], wq2[i * HD + j], acc);
    qv[j] = acc;
    __syncthreads();
    float s = 0.0f;
#pragma unroll
    for (int h = 0; h < HD; ++h) s = fmaf(wk2[j * HD + h], qv[h], s);
    const float val = s * 0.18033688011112042f;   // (1/8)*log2(e)
    qks_g[(size_t)b * HD + j] = val;
    float mb = __builtin_fabsf(val);
#pragma unroll
    for (int o = 32; o > 0; o >>= 1) mb += __shfl_xor(mb, o, 64);
    if (j == 0) Mb_g[b] = mb;
}

// K1: one block per b. Waves 0-1 (t<128): score producers (R1-proven scalar
// math). Waves 2-3: context consumers streaming TO, one chunk behind through
// LDS. VGPR cap 128 (NOT 64 — R2's spill bug) so the producer hot loop stays
// in registers and score VALU hides under the consumer's BW-bound stream.
__global__ __launch_bounds__(256, 4) void prodcons_attn(
    const float* __restrict__ pwp,   // [B, N, 24]
    const float* __restrict__ to,    // [B, N, 128]
    const float* __restrict__ wk1,   // [24, 64]
    const float* __restrict__ bk1,   // [64]
    const float* __restrict__ qks_g, // [B, 64]  (pre-scaled)
    const float* __restrict__ Mb_g,  // [B]
    float* __restrict__ out_ctx,     // [B, 128]
    float* __restrict__ out_attn)    // [B, N]
{
    const int b = blockIdx.x;
    const int t = threadIdx.x;

    __shared__ float  p_all[NN];     // exp2(s - Mb) for all 512 rows
    __shared__ float  qks[HD];
    __shared__ float4 part[4][32];

    if (t < HD) qks[t] = qks_g[(size_t)b * HD + t];
    const float Mb = Mb_g[b];        // uniform load (cached)
    __syncthreads();

    const bool is_prod = (t < 128);
    const int ct = t - 128;          // consumer id (valid when !is_prod)
    const int g  = ct & 31;          // float4 column group 0..31
    const int r  = (ct >> 5) & 3;    // row partition 0..3

    const float4* trow = reinterpret_cast<const float4*>(to + (size_t)b * NN * DO) + g;
    float4 acc = make_float4(0.f, 0.f, 0.f, 0.f);

    auto consume = [&](int cc) {
        const int n0 = cc * CHUNK + r * 32;
#pragma unroll 8
        for (int i = 0; i < 32; ++i) {
            const int n = n0 + i;
            const float p = p_all[n];          // half-wave broadcast
            float4 v = trow[(size_t)n * (DO / 4)];
            acc.x = fmaf(p, v.x, acc.x);
            acc.y = fmaf(p, v.y, acc.y);
            acc.z = fmaf(p, v.z, acc.z);
            acc.w = fmaf(p, v.w, acc.w);
        }
    };

    const float4* wk1_4 = reinterpret_cast<const float4*>(wk1);
    const float4* bk1_4 = reinterpret_cast<const float4*>(bk1);
    const float4* qks_4 = reinterpret_cast<const float4*>(qks);

    // ---------- pipelined chunk loop ----------
    for (int c = 0; c < NCHUNK; ++c) {
        if (is_prod) {
            const int n = c * CHUNK + t;
            const float* prow = pwp + ((size_t)b * NN + n) * KD;
            float x[KD];
#pragma unroll
            for (int i = 0; i < KD / 4; ++i)
                reinterpret_cast<float4*>(x)[i] =
                    reinterpret_cast<const float4*>(prow)[i];
            float sc = 0.0f;
#pragma unroll 2
            for (int j4 = 0; j4 < HD / 4; ++j4) {
                float4 bb = bk1_4[j4];                 // uniform -> scalar
                float a0 = bb.x, a1 = bb.y, a2 = bb.z, a3 = bb.w;
#pragma unroll
                for (int k = 0; k < KD; ++k) {
                    float4 w = wk1_4[k * (HD / 4) + j4];  // uniform -> scalar
                    a0 = fmaf(x[k], w.x, a0); a1 = fmaf(x[k], w.y, a1);
                    a2 = fmaf(x[k], w.z, a2); a3 = fmaf(x[k], w.w, a3);
                }
                float4 qq = qks_4[j4];                 // LDS broadcast
                sc = fmaf(fast_tanh(a0), qq.x, sc);
                sc = fmaf(fast_tanh(a1), qq.y, sc);
                sc = fmaf(fast_tanh(a2), qq.z, sc);
                sc = fmaf(fast_tanh(a3), qq.w, sc);
            }
            p_all[n] = __builtin_amdgcn_exp2f(sc - Mb);
        } else if (c > 0) {
            consume(c - 1);
        }
        __syncthreads();
    }

    // ---------- epilogue ----------
    float invL = 0.0f;
    if (!is_prod) {
        consume(NCHUNK - 1);         // last chunk (p_all fully written)
        part[r][g] = acc;
    } else if (t < 64) {
        // wave 0: denominator + attn output, overlapped with consumers' tail
        float l = 0.0f;
#pragma unroll
        for (int i = 0; i < NN / 64; ++i) l += p_all[t + 64 * i];
#pragma unroll
        for (int o = 32; o > 0; o >>= 1) l += __shfl_xor(l, o, 64);
        invL = __builtin_amdgcn_rcpf(l);
        float* oa = out_attn + (size_t)b * NN;
#pragma unroll
        for (int i = 0; i < NN / 64; ++i) oa[t + 64 * i] = p_all[t + 64 * i] * invL;
    }
    __syncthreads();

    if (t < 32) {                    // wave 0 still holds invL
        float4 r0 = part[0][t], r1 = part[1][t], r2 = part[2][t], r3 = part[3][t];
        float4 o;
        o.x = ((r0.x + r1.x) + (r2.x + r3.x)) * invL;
        o.y = ((r0.y + r1.y) + (r2.y + r3.y)) * invL;
        o.z = ((r0.z + r1.z) + (r2.z + r3.z)) * invL;
        o.w = ((r0.w + r1.w) + (r2.w + r3.w)) * invL;
        reinterpret_cast<float4*>(out_ctx + (size_t)b * DO)[t] = o;
    }
}

extern "C" void kernel_launch(void* const* d_in, const int* in_sizes, int n_in,
                              void* d_out, int out_size, void* d_ws, size_t ws_size,
                              hipStream_t stream) {
    const float* fwp = (const float*)d_in[0];
    const float* pwp = (const float*)d_in[1];
    const float* to  = (const float*)d_in[2];
    const float* wq1 = (const float*)d_in[3];
    const float* bq1 = (const float*)d_in[4];
    const float* wq2 = (const float*)d_in[5];
    const float* bq2 = (const float*)d_in[6];
    const float* wk1 = (const float*)d_in[7];
    const float* bk1 = (const float*)d_in[8];
    const float* wk2 = (const float*)d_in[9];
    // d_in[10] = bk2: per-row constant in scores -> cancels in softmax.

    float* out      = (float*)d_out;
    const int B     = in_sizes[0] / QD;         // 2048
    float* out_ctx  = out;
    float* out_attn = out + (size_t)B * DO;

    float* qks_g = (float*)d_ws;                // B*64 floats
    float* Mb_g  = qks_g + (size_t)B * HD;      // B floats

    qk_proj<<<B, 64, 0, stream>>>(fwp, wq1, bq1, wq2, bq2, wk2, qks_g, Mb_g);
    prodcons_attn<<<B, 256, 0, stream>>>(pwp, to, wk1, bk1, qks_g, Mb_g,
                                         out, out + (size_t)B * DO);
}

// Round 6
// 138.501 us; speedup vs baseline: 1.2533x; 1.0551x over previous
//
#include <hip/hip_runtime.h>
#include <math.h>

#define QD 24
#define KD 24
#define HD 64
#define NN 512
#define DO 128

__device__ __forceinline__ float fast_tanh(float x) {
    // tanh(x) = sign(x) * (1 - e^{-2|x|}) / (1 + e^{-2|x|}); exp via exp2
    float ax = __builtin_fabsf(x);
    float t  = __builtin_amdgcn_exp2f(-2.885390081777927f * ax); // -2*log2(e)*|x|
    float r  = (1.0f - t) * __builtin_amdgcn_rcpf(1.0f + t);
    return __builtin_copysignf(r, x);
}

// Kernel A: qk[b,j] = sum_h wk2[j,h] * q[b,h], pre-scaled by 0.125*log2(e).
// q = tanh(fwp @ wq1 + bq1) @ wq2 + bq2. One 64-thread block per b.
// (bk2 adds a per-row constant to every score -> cancels in softmax.)
__global__ __launch_bounds__(64) void qk_proj(
    const float* __restrict__ fwp,
    const float* __restrict__ wq1, const float* __restrict__ bq1,
    const float* __restrict__ wq2, const float* __restrict__ bq2,
    const float* __restrict__ wk2,
    float* __restrict__ qk_out)
{
    const int b = blockIdx.x;
    const int j = threadIdx.x;
    __shared__ float xf[QD];
    __shared__ float h1[HD];
    __shared__ float qv[HD];
    if (j < QD) xf[j] = fwp[b * QD + j];
    __syncthreads();
    float acc = bq1[j];
#pragma unroll
    for (int k = 0; k < QD; ++k) acc = fmaf(xf[k], wq1[k * HD + j], acc);
    h1[j] = fast_tanh(acc);
    __syncthreads();
    acc = bq2[j];
#pragma unroll
    for (int i = 0; i < HD; ++i) acc = fmaf(h1[i], wq2[i * HD + j], acc);
    qv[j] = acc;
    __syncthreads();
    float s = 0.0f;
#pragma unroll
    for (int h = 0; h < HD; ++h) s = fmaf(wk2[j * HD + h], qv[h], s);
    qk_out[b * HD + j] = s * 0.18033688011112042f;  // (1/8)*log2(e)
}

// Kernel B (R1 structure + channel-stagger in phase 2).
__global__ __launch_bounds__(256) void attn_ctx(
    const float* __restrict__ pwp,   // [B, N, 24]
    const float* __restrict__ to,    // [B, N, 128]
    const float* __restrict__ wk1,   // [24, 64]
    const float* __restrict__ bk1,   // [64]
    const float* __restrict__ qk,    // [B, 64], pre-scaled
    float* __restrict__ out_ctx,     // [B, 128]
    float* __restrict__ out_attn)    // [B, N]
{
    const int b = blockIdx.x;
    const int t = threadIdx.x;

    __shared__ float  s_attn[NN];
    __shared__ float  s_red[8];
    __shared__ float4 s_part[8][32];

    // ---- Phase 1: two score rows per thread (rows t and t+256) ----
    const float* prow0 = pwp + (size_t)b * NN * KD + (size_t)t * KD;
    float x0[KD], x1[KD];
#pragma unroll
    for (int i = 0; i < KD / 4; ++i) {
        float4 v0 = reinterpret_cast<const float4*>(prow0)[i];
        float4 v1 = reinterpret_cast<const float4*>(prow0 + 256 * KD)[i];
        x0[4 * i + 0] = v0.x; x0[4 * i + 1] = v0.y; x0[4 * i + 2] = v0.z; x0[4 * i + 3] = v0.w;
        x1[4 * i + 0] = v1.x; x1[4 * i + 1] = v1.y; x1[4 * i + 2] = v1.z; x1[4 * i + 3] = v1.w;
    }

    const float4* wk1_4 = reinterpret_cast<const float4*>(wk1);
    const float4* bk1_4 = reinterpret_cast<const float4*>(bk1);
    const float4* qk_4  = reinterpret_cast<const float4*>(qk + (size_t)b * HD);

    float sc0 = 0.0f, sc1 = 0.0f;
#pragma unroll 2
    for (int j4 = 0; j4 < HD / 4; ++j4) {
        float4 bb = bk1_4[j4];            // uniform -> scalar load
        float a00 = bb.x, a01 = bb.y, a02 = bb.z, a03 = bb.w;
        float a10 = bb.x, a11 = bb.y, a12 = bb.z, a13 = bb.w;
#pragma unroll
        for (int k = 0; k < KD; ++k) {
            float4 w = wk1_4[k * (HD / 4) + j4];  // uniform -> scalar load
            a00 = fmaf(x0[k], w.x, a00); a01 = fmaf(x0[k], w.y, a01);
            a02 = fmaf(x0[k], w.z, a02); a03 = fmaf(x0[k], w.w, a03);
            a10 = fmaf(x1[k], w.x, a10); a11 = fmaf(x1[k], w.y, a11);
            a12 = fmaf(x1[k], w.z, a12); a13 = fmaf(x1[k], w.w, a13);
        }
        float4 qv = qk_4[j4];             // uniform -> scalar load
        sc0 = fmaf(fast_tanh(a00), qv.x, sc0);
        sc0 = fmaf(fast_tanh(a01), qv.y, sc0);
        sc0 = fmaf(fast_tanh(a02), qv.z, sc0);
        sc0 = fmaf(fast_tanh(a03), qv.w, sc0);
        sc1 = fmaf(fast_tanh(a10), qv.x, sc1);
        sc1 = fmaf(fast_tanh(a11), qv.y, sc1);
        sc1 = fmaf(fast_tanh(a12), qv.z, sc1);
        sc1 = fmaf(fast_tanh(a13), qv.w, sc1);
    }

    // ---- softmax over 512 scores (scores already in exp2 domain) ----
    float m = fmaxf(sc0, sc1);
#pragma unroll
    for (int o = 32; o > 0; o >>= 1) m = fmaxf(m, __shfl_xor(m, o, 64));
    const int wid  = t >> 6;
    const int lane = t & 63;
    if (lane == 0) s_red[wid] = m;
    __syncthreads();
    m = fmaxf(fmaxf(s_red[0], s_red[1]), fmaxf(s_red[2], s_red[3]));

    float e0 = __builtin_amdgcn_exp2f(sc0 - m);
    float e1 = __builtin_amdgcn_exp2f(sc1 - m);
    float ss = e0 + e1;
#pragma unroll
    for (int o = 32; o > 0; o >>= 1) ss += __shfl_xor(ss, o, 64);
    if (lane == 0) s_red[4 + wid] = ss;   // disjoint slots
    __syncthreads();
    ss = (s_red[4] + s_red[5]) + (s_red[6] + s_red[7]);

    const float inv = __builtin_amdgcn_rcpf(ss);
    const float a0 = e0 * inv, a1 = e1 * inv;
    s_attn[t]       = a0;
    s_attn[t + 256] = a1;
    out_attn[(size_t)b * NN + t]       = a0;
    out_attn[(size_t)b * NN + t + 256] = a1;
    __syncthreads();

    // ---- Phase 2: context[b,:] = sum_n attn[n] * TO[b,n,:] ----
    // Channel-stagger: rotate each block/partition's row order so concurrent
    // addresses across the device cover all HBM channels instead of
    // phase-locking on a few (TO blocks are 256KB-aligned streams).
    const int g  = t & 31;   // float4 group within the 128-wide row
    const int np = t >> 5;   // n-partition 0..7 (64 rows each)
    const int rot = ((b * 7) + np * 9) & 63;
    const float4* trow = reinterpret_cast<const float4*>(to + (size_t)b * NN * DO) + g;
    float4 acc = make_float4(0.f, 0.f, 0.f, 0.f);
#pragma unroll 8
    for (int i = 0; i < NN / 8; ++i) {
        const int n = np * (NN / 8) + ((i + rot) & 63);
        const float a = s_attn[n];        // uniform per 32-lane group
        float4 v = trow[(size_t)n * (DO / 4)];
        acc.x = fmaf(a, v.x, acc.x);
        acc.y = fmaf(a, v.y, acc.y);
        acc.z = fmaf(a, v.z, acc.z);
        acc.w = fmaf(a, v.w, acc.w);
    }
    s_part[np][g] = acc;
    __syncthreads();
    if (t < 32) {
        float4 r = s_part[0][t];
#pragma unroll
        for (int p = 1; p < 8; ++p) {
            float4 v = s_part[p][t];
            r.x += v.x; r.y += v.y; r.z += v.z; r.w += v.w;
        }
        reinterpret_cast<float4*>(out_ctx + (size_t)b * DO)[t] = r;
    }
}

extern "C" void kernel_launch(void* const* d_in, const int* in_sizes, int n_in,
                              void* d_out, int out_size, void* d_ws, size_t ws_size,
                              hipStream_t stream) {
    const float* fwp = (const float*)d_in[0];
    const float* pwp = (const float*)d_in[1];
    const float* to  = (const float*)d_in[2];
    const float* wq1 = (const float*)d_in[3];
    const float* bq1 = (const float*)d_in[4];
    const float* wq2 = (const float*)d_in[5];
    const float* bq2 = (const float*)d_in[6];
    const float* wk1 = (const float*)d_in[7];
    const float* bk1 = (const float*)d_in[8];
    const float* wk2 = (const float*)d_in[9];
    // d_in[10] = bk2: per-row constant in scores -> cancels in softmax.

    float* out = (float*)d_out;
    float* qk  = (float*)d_ws;                 // B*64 floats
    const int B = in_sizes[0] / QD;            // 2048

    qk_proj<<<B, 64, 0, stream>>>(fwp, wq1, bq1, wq2, bq2, wk2, qk);
    attn_ctx<<<B, 256, 0, stream>>>(pwp, to, wk1, bk1, qk, out,
                                    out + (size_t)B * DO);
}

// Round 7
// 131.967 us; speedup vs baseline: 1.3153x; 1.0495x over previous
//
#include <hip/hip_runtime.h>
#include <math.h>

#define QD 24
#define KD 24
#define HD 64
#define NN 512
#define DO 128

__device__ __forceinline__ float fast_tanh(float x) {
    // tanh(x) = sign(x) * (1 - e^{-2|x|}) / (1 + e^{-2|x|}); exp via exp2
    float ax = __builtin_fabsf(x);
    float t  = __builtin_amdgcn_exp2f(-2.885390081777927f * ax); // -2*log2(e)*|x|
    float r  = (1.0f - t) * __builtin_amdgcn_rcpf(1.0f + t);
    return __builtin_copysignf(r, x);
}

// One 256-thread block per b. Fully fused, barrier-free main loop:
//  - prologue (wave 0): q = L-T-L(fwp); qks = (wk2 @ q) * (1/8)log2e in LDS.
//    bk2 cancels in softmax; fixed shift Mb = sum|qks| bounds all scores
//    (|tanh| <= 1) -> p = exp2(s - Mb) per-row, normalization deferred.
//  - main: wave w handles chunks {w, w+4} of 64 rows. Per chunk: 64 scores
//    (one/lane), p -> LDS (own slice, same-wave DS order, no barrier), then
//    stream 64 TO rows (32 coalesced 1KB wave-loads, 2 rows/instr).
//    Waves drift freely -> score VALU of some waves hides under other
//    waves' HBM streaming at instruction granularity.
__global__ __launch_bounds__(256, 4) void fused_attn(
    const float* __restrict__ fwp,   // [B, 24]
    const float* __restrict__ pwp,   // [B, N, 24]
    const float* __restrict__ to,    // [B, N, 128]
    const float* __restrict__ wq1, const float* __restrict__ bq1,
    const float* __restrict__ wq2, const float* __restrict__ bq2,
    const float* __restrict__ wk1, const float* __restrict__ bk1,
    const float* __restrict__ wk2,
    float* __restrict__ out_ctx,     // [B, 128]
    float* __restrict__ out_attn)    // [B, N]
{
    const int b    = blockIdx.x;
    const int t    = threadIdx.x;
    const int wave = t >> 6;
    const int lane = t & 63;
    const int g    = lane & 31;      // float4 column 0..31
    const int h    = lane >> 5;      // half-wave 0/1

    __shared__ float  qks[HD];
    __shared__ float  h1s[HD];
    __shared__ float  qvs[HD];
    __shared__ float  s_attn[NN];    // unnormalized p for all rows
    __shared__ float  s_red[4];
    __shared__ float4 s_part[8][32];

    const int n0 = wave * 64 + lane;         // round-0 row
    const int n1 = n0 + 4 * 64;              // round-1 row

    // issue round-0 pwp loads immediately (complete under prologue)
    const float* prow0 = pwp + ((size_t)b * NN + n0) * KD;
    float x[KD];
#pragma unroll
    for (int i = 0; i < KD / 4; ++i)
        reinterpret_cast<float4*>(x)[i] = reinterpret_cast<const float4*>(prow0)[i];

    // ---------- prologue: Q-path on threads t<64 ----------
    if (t < HD) {
        float xf[QD];
#pragma unroll
        for (int i = 0; i < QD / 4; ++i)   // uniform address -> s_load
            reinterpret_cast<float4*>(xf)[i] =
                reinterpret_cast<const float4*>(fwp + (size_t)b * QD)[i];
        float a = bq1[t];
#pragma unroll
        for (int k = 0; k < QD; ++k) a = fmaf(xf[k], wq1[k * HD + t], a);
        h1s[t] = fast_tanh(a);
    }
    __syncthreads();
    if (t < HD) {
        float a = bq2[t];
#pragma unroll
        for (int i = 0; i < HD; ++i) a = fmaf(h1s[i], wq2[i * HD + t], a);
        qvs[t] = a;
    }
    __syncthreads();
    if (t < HD) {
        float s = 0.0f;
#pragma unroll
        for (int hh = 0; hh < HD; ++hh) s = fmaf(wk2[t * HD + hh], qvs[hh], s);
        qks[t] = s * 0.18033688011112042f;   // (1/8) * log2(e)
    }
    __syncthreads();

    float Mb = 0.0f;                 // fixed softmax shift (upper bound)
#pragma unroll
    for (int hh = 0; hh < HD; ++hh) Mb += __builtin_fabsf(qks[hh]);

    const float4* wk1_4 = reinterpret_cast<const float4*>(wk1);
    const float4* bk1_4 = reinterpret_cast<const float4*>(bk1);
    const float4* qks_4 = reinterpret_cast<const float4*>(qks);
    const float4* trow  = reinterpret_cast<const float4*>(to + (size_t)b * NN * DO) + g;

    float4 acc = make_float4(0.f, 0.f, 0.f, 0.f);
    float Lloc = 0.0f;

    auto score_one = [&](const float* xr) -> float {
        float sc = 0.0f;
#pragma unroll 2
        for (int j4 = 0; j4 < HD / 4; ++j4) {
            float4 bb = bk1_4[j4];                    // uniform -> scalar
            float a0 = bb.x, a1 = bb.y, a2 = bb.z, a3 = bb.w;
#pragma unroll
            for (int k = 0; k < KD; ++k) {
                float4 w = wk1_4[k * (HD / 4) + j4];  // uniform -> scalar
                a0 = fmaf(xr[k], w.x, a0); a1 = fmaf(xr[k], w.y, a1);
                a2 = fmaf(xr[k], w.z, a2); a3 = fmaf(xr[k], w.w, a3);
            }
            float4 qq = qks_4[j4];                    // LDS broadcast
            sc = fmaf(fast_tanh(a0), qq.x, sc);
            sc = fmaf(fast_tanh(a1), qq.y, sc);
            sc = fmaf(fast_tanh(a2), qq.z, sc);
            sc = fmaf(fast_tanh(a3), qq.w, sc);
        }
        return sc;
    };

    auto stream_chunk = [&](int chunk) {
        const int base = chunk * 64;
#pragma unroll 8
        for (int i = 0; i < 32; ++i) {
            const int row = base + 2 * i + h;
            const float p = s_attn[row];   // 2 addrs/wave -> LDS broadcast
            float4 v = trow[(size_t)row * (DO / 4)];
            acc.x = fmaf(p, v.x, acc.x);
            acc.y = fmaf(p, v.y, acc.y);
            acc.z = fmaf(p, v.z, acc.z);
            acc.w = fmaf(p, v.w, acc.w);
        }
    };

    // ---------- round 0 ----------
    const float p0 = __builtin_amdgcn_exp2f(score_one(x) - Mb);
    s_attn[n0] = p0;                 // same-wave DS ordering; no barrier
    Lloc += p0;

    // prefetch round-1 pwp row (hides under chunk-0 stream)
    const float* prow1 = pwp + ((size_t)b * NN + n1) * KD;
    float x1[KD];
#pragma unroll
    for (int i = 0; i < KD / 4; ++i)
        reinterpret_cast<float4*>(x1)[i] = reinterpret_cast<const float4*>(prow1)[i];

    stream_chunk(wave);

    // ---------- round 1 ----------
    const float p1 = __builtin_amdgcn_exp2f(score_one(x1) - Mb);
    s_attn[n1] = p1;
    Lloc += p1;
    stream_chunk(wave + 4);

    // ---------- epilogue ----------
#pragma unroll
    for (int o = 32; o > 0; o >>= 1) Lloc += __shfl_xor(Lloc, o, 64);
    if (lane == 0) s_red[wave] = Lloc;
    s_part[wave * 2 + h][g] = acc;
    __syncthreads();

    const float L    = (s_red[0] + s_red[1]) + (s_red[2] + s_red[3]);
    const float invL = __builtin_amdgcn_rcpf(L);

    out_attn[(size_t)b * NN + t]       = s_attn[t] * invL;
    out_attn[(size_t)b * NN + t + 256] = s_attn[t + 256] * invL;

    if (t < 32) {
        float4 r = s_part[0][t];
#pragma unroll
        for (int q = 1; q < 8; ++q) {
            float4 v = s_part[q][t];
            r.x += v.x; r.y += v.y; r.z += v.z; r.w += v.w;
        }
        float4 o;
        o.x = r.x * invL; o.y = r.y * invL; o.z = r.z * invL; o.w = r.w * invL;
        reinterpret_cast<float4*>(out_ctx + (size_t)b * DO)[t] = o;
    }
}

extern "C" void kernel_launch(void* const* d_in, const int* in_sizes, int n_in,
                              void* d_out, int out_size, void* d_ws, size_t ws_size,
                              hipStream_t stream) {
    const float* fwp = (const float*)d_in[0];
    const float* pwp = (const float*)d_in[1];
    const float* to  = (const float*)d_in[2];
    const float* wq1 = (const float*)d_in[3];
    const float* bq1 = (const float*)d_in[4];
    const float* wq2 = (const float*)d_in[5];
    const float* bq2 = (const float*)d_in[6];
    const float* wk1 = (const float*)d_in[7];
    const float* bk1 = (const float*)d_in[8];
    const float* wk2 = (const float*)d_in[9];
    // d_in[10] = bk2: per-row constant in scores -> cancels in softmax.

    float* out  = (float*)d_out;
    const int B = in_sizes[0] / QD;  // 2048

    fused_attn<<<B, 256, 0, stream>>>(fwp, pwp, to, wq1, bq1, wq2, bq2,
                                      wk1, bk1, wk2,
                                      out, out + (size_t)B * DO);
}

// Round 9
// 115.980 us; speedup vs baseline: 1.4966x; 1.1378x over previous
//
#include <hip/hip_runtime.h>
#include <math.h>

#define QD 24
#define KD 24
#define HD 64
#define NN 512
#define DO 128

typedef float v4f __attribute__((ext_vector_type(4)));

__device__ __forceinline__ float fast_tanh(float x) {
    // tanh(x) = sign(x) * (1 - e^{-2|x|}) / (1 + e^{-2|x|}); exp via exp2
    float ax = __builtin_fabsf(x);
    float t  = __builtin_amdgcn_exp2f(-2.885390081777927f * ax); // -2*log2(e)*|x|
    float r  = (1.0f - t) * __builtin_amdgcn_rcpf(1.0f + t);
    return __builtin_copysignf(r, x);
}

// One 256-thread block per b. Fully fused, barrier-free main loop (R7),
// with NONTEMPORAL loads (native clang vector type) for the 537MB TO
// stream: read-once data bypasses L2 allocation instead of thrashing it.
__global__ __launch_bounds__(256, 4) void fused_attn(
    const float* __restrict__ fwp,   // [B, 24]
    const float* __restrict__ pwp,   // [B, N, 24]
    const float* __restrict__ to,    // [B, N, 128]
    const float* __restrict__ wq1, const float* __restrict__ bq1,
    const float* __restrict__ wq2, const float* __restrict__ bq2,
    const float* __restrict__ wk1, const float* __restrict__ bk1,
    const float* __restrict__ wk2,
    float* __restrict__ out_ctx,     // [B, 128]
    float* __restrict__ out_attn)    // [B, N]
{
    const int b    = blockIdx.x;
    const int t    = threadIdx.x;
    const int wave = t >> 6;
    const int lane = t & 63;
    const int g    = lane & 31;      // float4 column 0..31
    const int h    = lane >> 5;      // half-wave 0/1

    __shared__ float  qks[HD];
    __shared__ float  h1s[HD];
    __shared__ float  qvs[HD];
    __shared__ float  s_attn[NN];    // unnormalized p for all rows
    __shared__ float  s_red[4];
    __shared__ v4f    s_part[8][32];

    const int n0 = wave * 64 + lane;         // round-0 row
    const int n1 = n0 + 4 * 64;              // round-1 row

    // issue round-0 pwp loads immediately (complete under prologue)
    const float* prow0 = pwp + ((size_t)b * NN + n0) * KD;
    float x[KD];
#pragma unroll
    for (int i = 0; i < KD / 4; ++i)
        reinterpret_cast<v4f*>(x)[i] = reinterpret_cast<const v4f*>(prow0)[i];

    // ---------- prologue: Q-path on threads t<64 ----------
    if (t < HD) {
        float xf[QD];
#pragma unroll
        for (int i = 0; i < QD / 4; ++i)
            reinterpret_cast<v4f*>(xf)[i] =
                reinterpret_cast<const v4f*>(fwp + (size_t)b * QD)[i];
        float a = bq1[t];
#pragma unroll
        for (int k = 0; k < QD; ++k) a = fmaf(xf[k], wq1[k * HD + t], a);
        h1s[t] = fast_tanh(a);
    }
    __syncthreads();
    if (t < HD) {
        float a = bq2[t];
#pragma unroll
        for (int i = 0; i < HD; ++i) a = fmaf(h1s[i], wq2[i * HD + t], a);
        qvs[t] = a;
    }
    __syncthreads();
    if (t < HD) {
        float s = 0.0f;
#pragma unroll
        for (int hh = 0; hh < HD; ++hh) s = fmaf(wk2[t * HD + hh], qvs[hh], s);
        qks[t] = s * 0.18033688011112042f;   // (1/8) * log2(e)
    }
    __syncthreads();

    float Mb = 0.0f;                 // fixed softmax shift (upper bound)
#pragma unroll
    for (int hh = 0; hh < HD; ++hh) Mb += __builtin_fabsf(qks[hh]);

    const v4f* wk1_4 = reinterpret_cast<const v4f*>(wk1);
    const v4f* bk1_4 = reinterpret_cast<const v4f*>(bk1);
    const v4f* qks_4 = reinterpret_cast<const v4f*>(qks);
    const v4f* trow  = reinterpret_cast<const v4f*>(to + (size_t)b * NN * DO) + g;

    v4f acc = (v4f){0.f, 0.f, 0.f, 0.f};
    float Lloc = 0.0f;

    auto score_one = [&](const float* xr) -> float {
        float sc = 0.0f;
#pragma unroll 2
        for (int j4 = 0; j4 < HD / 4; ++j4) {
            v4f bb = bk1_4[j4];                       // uniform -> scalar
            float a0 = bb.x, a1 = bb.y, a2 = bb.z, a3 = bb.w;
#pragma unroll
            for (int k = 0; k < KD; ++k) {
                v4f w = wk1_4[k * (HD / 4) + j4];     // uniform -> scalar
                a0 = fmaf(xr[k], w.x, a0); a1 = fmaf(xr[k], w.y, a1);
                a2 = fmaf(xr[k], w.z, a2); a3 = fmaf(xr[k], w.w, a3);
            }
            v4f qq = qks_4[j4];                       // LDS broadcast
            sc = fmaf(fast_tanh(a0), qq.x, sc);
            sc = fmaf(fast_tanh(a1), qq.y, sc);
            sc = fmaf(fast_tanh(a2), qq.z, sc);
            sc = fmaf(fast_tanh(a3), qq.w, sc);
        }
        return sc;
    };

    auto stream_chunk = [&](int chunk) {
        const int base = chunk * 64;
#pragma unroll 8
        for (int i = 0; i < 32; ++i) {
            const int row = base + 2 * i + h;
            const float p = s_attn[row];   // 2 addrs/wave -> LDS broadcast
            v4f v = __builtin_nontemporal_load(&trow[(size_t)row * (DO / 4)]);
            acc.x = fmaf(p, v.x, acc.x);
            acc.y = fmaf(p, v.y, acc.y);
            acc.z = fmaf(p, v.z, acc.z);
            acc.w = fmaf(p, v.w, acc.w);
        }
    };

    // ---------- round 0 ----------
    const float p0 = __builtin_amdgcn_exp2f(score_one(x) - Mb);
    s_attn[n0] = p0;                 // same-wave DS ordering; no barrier
    Lloc += p0;

    // prefetch round-1 pwp row (hides under chunk-0 stream)
    const float* prow1 = pwp + ((size_t)b * NN + n1) * KD;
    float x1[KD];
#pragma unroll
    for (int i = 0; i < KD / 4; ++i)
        reinterpret_cast<v4f*>(x1)[i] = reinterpret_cast<const v4f*>(prow1)[i];

    stream_chunk(wave);

    // ---------- round 1 ----------
    const float p1 = __builtin_amdgcn_exp2f(score_one(x1) - Mb);
    s_attn[n1] = p1;
    Lloc += p1;
    stream_chunk(wave + 4);

    // ---------- epilogue ----------
#pragma unroll
    for (int o = 32; o > 0; o >>= 1) Lloc += __shfl_xor(Lloc, o, 64);
    if (lane == 0) s_red[wave] = Lloc;
    s_part[wave * 2 + h][g] = acc;
    __syncthreads();

    const float L    = (s_red[0] + s_red[1]) + (s_red[2] + s_red[3]);
    const float invL = __builtin_amdgcn_rcpf(L);

    out_attn[(size_t)b * NN + t]       = s_attn[t] * invL;
    out_attn[(size_t)b * NN + t + 256] = s_attn[t + 256] * invL;

    if (t < 32) {
        v4f r = s_part[0][t];
#pragma unroll
        for (int q = 1; q < 8; ++q) {
            v4f v = s_part[q][t];
            r.x += v.x; r.y += v.y; r.z += v.z; r.w += v.w;
        }
        v4f o;
        o.x = r.x * invL; o.y = r.y * invL; o.z = r.z * invL; o.w = r.w * invL;
        reinterpret_cast<v4f*>(out_ctx + (size_t)b * DO)[t] = o;
    }
}

extern "C" void kernel_launch(void* const* d_in, const int* in_sizes, int n_in,
                              void* d_out, int out_size, void* d_ws, size_t ws_size,
                              hipStream_t stream) {
    const float* fwp = (const float*)d_in[0];
    const float* pwp = (const float*)d_in[1];
    const float* to  = (const float*)d_in[2];
    const float* wq1 = (const float*)d_in[3];
    const float* bq1 = (const float*)d_in[4];
    const float* wq2 = (const float*)d_in[5];
    const float* bq2 = (const float*)d_in[6];
    const float* wk1 = (const float*)d_in[7];
    const float* bk1 = (const float*)d_in[8];
    const float* wk2 = (const float*)d_in[9];
    // d_in[10] = bk2: per-row constant in scores -> cancels in softmax.

    float* out  = (float*)d_out;
    const int B = in_sizes[0] / QD;  // 2048

    fused_attn<<<B, 256, 0, stream>>>(fwp, pwp, to, wq1, bq1, wq2, bq2,
                                      wk1, bk1, wk2,
                                      out, out + (size_t)B * DO);
}